// Round 2
// baseline (3275.487 us; speedup 1.0000x reference)
//
#include <hip/hip_runtime.h>
#include <hip/hip_bf16.h>

// V=32000 E=512 H=512 L=2 B=64 ML=64 T=32 -- float32 in/out, bf16 MFMA internally
typedef __bf16 bf16_t;
typedef bf16_t bf16x8 __attribute__((ext_vector_type(8)));
typedef float f32x4 __attribute__((ext_vector_type(4)));

#define MFMA(a, b, c) __builtin_amdgcn_mfma_f32_16x16x32_bf16((a), (b), (c), 0, 0, 0)

__device__ __forceinline__ float sigm(float x) { return 1.f / (1.f + __expf(-x)); }
__device__ __forceinline__ float tanh_f(float x) { return 1.f - 2.f / (__expf(2.f * x) + 1.f); }

__device__ __forceinline__ bf16x8 cvt8(const float* p) {
    f32x4 a = *(const f32x4*)p, b = *(const f32x4*)(p + 4);
    bf16x8 v;
#pragma unroll
    for (int i = 0; i < 4; ++i) { v[i] = (bf16_t)a[i]; v[4 + i] = (bf16_t)b[i]; }
    return v;
}

// ---------- f32 -> bf16 weight conversion (n % 8 == 0) ----------
__global__ void k_cvt(const float* __restrict__ src, bf16_t* __restrict__ dst, int n) {
    int i = (blockIdx.x * 256 + threadIdx.x) * 8;
    if (i < n) *(bf16x8*)(dst + i) = cvt8(src + i);
}

// ---------- init: c (fp32), h parity-0 (bf16), bias sums (fp32) ----------
__global__ void k_init(const float* __restrict__ h0, const float* __restrict__ c0,
                       const float* __restrict__ bi, const float* __restrict__ bh,
                       float* __restrict__ c_f32, bf16_t* __restrict__ h_bf,
                       float* __restrict__ bsum) {
    int idx = blockIdx.x * 256 + threadIdx.x;
    if (idx < 65536) { c_f32[idx] = c0[idx]; h_bf[idx] = (bf16_t)h0[idx]; }
    if (idx < 4096) bsum[idx] = bi[idx] + bh[idx];
}

// ---------- precompute emb-dependent GEMMs: out[M,N] = Emb[tok](f32->bf16) @ Bm[:, koff:+512]^T ----------
__global__ __launch_bounds__(256) void k_pre(const float* __restrict__ emb,
                                             const int* __restrict__ cur, const int* __restrict__ gt,
                                             const bf16_t* __restrict__ Bm, int ldb, int koff,
                                             float* __restrict__ out, int ldo) {
    int tid = threadIdx.x, lane = tid & 63, w = tid >> 6;
    int m = lane & 15, q = lane >> 4;
    int mrow = blockIdx.x * 64 + w * 16 + m;
    int tok = (mrow < 64) ? cur[mrow] : gt[mrow - 64];
    const float* arow = emb + (size_t)tok * 512;
    int n0 = blockIdx.y * 64;
    const bf16_t* brow0 = Bm + (size_t)(n0 + m) * ldb + koff;
    f32x4 acc[4] = {};
    for (int ks = 0; ks < 16; ++ks) {
        int kc = ks * 32 + q * 8;
        bf16x8 a = cvt8(arow + kc);
#pragma unroll
        for (int nt = 0; nt < 4; ++nt) {
            bf16x8 b = *(const bf16x8*)(brow0 + (size_t)nt * 16 * ldb + kc);
            acc[nt] = MFMA(a, b, acc[nt]);
        }
    }
    int rbase = blockIdx.x * 64 + w * 16 + q * 4;
#pragma unroll
    for (int nt = 0; nt < 4; ++nt)
#pragma unroll
        for (int i = 0; i < 4; ++i)
            out[(size_t)(rbase + i) * ldo + n0 + nt * 16 + m] = acc[nt][i];
}

// ---------- per-step fused attention: scores -> softmax -> ctx -> rnn_in ----------
__global__ __launch_bounds__(256) void k_attn_rnn(int t, const bf16_t* __restrict__ h2,
                                                  const bf16_t* __restrict__ attn_W,
                                                  const bf16_t* __restrict__ attn_out_W,
                                                  const float* __restrict__ enc,
                                                  const float* __restrict__ pre_s,
                                                  const float* __restrict__ pre_r,
                                                  bf16_t* __restrict__ rnn_bf) {
    __shared__ float s_p[8][64];
    __shared__ bf16_t s_ctx[16][520];
    int tid = threadIdx.x, lane = tid & 63, w = tid >> 6;
    int m = lane & 15, q = lane >> 4;
    int b0 = blockIdx.x * 8;
    for (int i = tid; i < 8 * 520; i += 256) s_ctx[8 + i / 520][i % 520] = (bf16_t)0.f;
    // phase 1: scores [8(pad16) x 64]
    {
        const bf16_t* aptr = h2 + (size_t)(b0 + (m & 7)) * 512;
        const bf16_t* bptr = attn_W + (size_t)(w * 16 + m) * 1024 + 512;
        f32x4 acc = {};
        for (int ks = 0; ks < 16; ++ks) {
            int kc = ks * 32 + q * 8;
            acc = MFMA(*(const bf16x8*)(aptr + kc), *(const bf16x8*)(bptr + kc), acc);
        }
#pragma unroll
        for (int i = 0; i < 4; ++i) {
            int mr = q * 4 + i;
            if (mr < 8)
                s_p[mr][w * 16 + m] = acc[i] + pre_s[((size_t)t * 64 + b0 + mr) * 64 + w * 16 + m];
        }
    }
    __syncthreads();
    // phase 2: softmax over ML=64
    if (tid < 8) {
        float mx = -1e30f;
        for (int l = 0; l < 64; ++l) mx = fmaxf(mx, s_p[tid][l]);
        float sum = 0.f;
        for (int l = 0; l < 64; ++l) { float e = __expf(s_p[tid][l] - mx); s_p[tid][l] = e; sum += e; }
        float inv = 1.f / sum;
        for (int l = 0; l < 64; ++l) s_p[tid][l] *= inv;
    }
    __syncthreads();
    // phase 3: ctx[b,:] = sum_l p[b,l] * enc[l,b,:]
    {
        int b = tid >> 5, g = tid & 31, h0 = g * 16;
        float acc[16];
#pragma unroll
        for (int i = 0; i < 16; ++i) acc[i] = 0.f;
        const float* ebase = enc + (size_t)(b0 + b) * 512 + h0;
        for (int l = 0; l < 64; ++l) {
            float a = s_p[b][l];
            const float* e = ebase + (size_t)l * 32768;
            f32x4 e0 = *(const f32x4*)(e), e1 = *(const f32x4*)(e + 4);
            f32x4 e2 = *(const f32x4*)(e + 8), e3 = *(const f32x4*)(e + 12);
#pragma unroll
            for (int i = 0; i < 4; ++i) {
                acc[i] += a * e0[i]; acc[4 + i] += a * e1[i];
                acc[8 + i] += a * e2[i]; acc[12 + i] += a * e3[i];
            }
        }
#pragma unroll
        for (int i = 0; i < 16; ++i) s_ctx[b][h0 + i] = (bf16_t)acc[i];
    }
    __syncthreads();
    // phase 4: rnn_in = relu(pre_r + ctx @ Wo[:,512:]^T)
    {
        f32x4 acc[8] = {};
        const bf16_t* actx = &s_ctx[m][0];
        const bf16_t* bbase = attn_out_W + (size_t)(w * 128 + m) * 1024 + 512;
        for (int ks = 0; ks < 16; ++ks) {
            int kc = ks * 32 + q * 8;
            bf16x8 a = *(const bf16x8*)(actx + kc);
#pragma unroll
            for (int nt = 0; nt < 8; ++nt) {
                bf16x8 b = *(const bf16x8*)(bbase + (size_t)nt * 16 * 1024 + kc);
                acc[nt] = MFMA(a, b, acc[nt]);
            }
        }
#pragma unroll
        for (int nt = 0; nt < 8; ++nt)
#pragma unroll
            for (int i = 0; i < 4; ++i) {
                int mr = q * 4 + i;
                if (mr < 8) {
                    int b = b0 + mr, j = w * 128 + nt * 16 + m;
                    float v = acc[nt][i] + pre_r[((size_t)t * 64 + b) * 512 + j];
                    rnn_bf[(size_t)b * 512 + j] = (bf16_t)fmaxf(v, 0.f);
                }
            }
    }
}

// ---------- LSTM cell ----------
__global__ __launch_bounds__(256) void k_lstm(const bf16_t* __restrict__ x,
                                              const bf16_t* __restrict__ hprev,
                                              const bf16_t* __restrict__ Wi,
                                              const bf16_t* __restrict__ Wh,
                                              const float* __restrict__ bsum,
                                              float* __restrict__ c,
                                              bf16_t* __restrict__ hout,
                                              bf16_t* __restrict__ xs_out) {
    int tid = threadIdx.x, lane = tid & 63, w = tid >> 6;
    int m = lane & 15, q = lane >> 4;
    int j0 = blockIdx.x * 16;
    const bf16_t* ax = x + (size_t)(w * 16 + m) * 512;
    const bf16_t* ah = hprev + (size_t)(w * 16 + m) * 512;
    f32x4 acc[4] = {};
    for (int ks = 0; ks < 16; ++ks) {
        int kc = ks * 32 + q * 8;
        bf16x8 a = *(const bf16x8*)(ax + kc);
#pragma unroll
        for (int g = 0; g < 4; ++g) {
            const bf16_t* bp = Wi + (size_t)(g * 512 + j0 + m) * 512 + kc;
            acc[g] = MFMA(a, *(const bf16x8*)bp, acc[g]);
        }
    }
    for (int ks = 0; ks < 16; ++ks) {
        int kc = ks * 32 + q * 8;
        bf16x8 a = *(const bf16x8*)(ah + kc);
#pragma unroll
        for (int g = 0; g < 4; ++g) {
            const bf16_t* bp = Wh + (size_t)(g * 512 + j0 + m) * 512 + kc;
            acc[g] = MFMA(a, *(const bf16x8*)bp, acc[g]);
        }
    }
    int j = j0 + m;
    float bs0 = bsum[j], bs1 = bsum[512 + j], bs2 = bsum[1024 + j], bs3 = bsum[1536 + j];
#pragma unroll
    for (int i = 0; i < 4; ++i) {
        int b = w * 16 + q * 4 + i;
        float ig = acc[0][i] + bs0;
        float fg = acc[1][i] + bs1;
        float gg = acc[2][i] + bs2;
        float og = acc[3][i] + bs3;
        size_t off = (size_t)b * 512 + j;
        float co = c[off];
        float cn = sigm(fg) * co + sigm(ig) * tanh_f(gg);
        float hn = sigm(og) * tanh_f(cn);
        c[off] = cn;
        hout[off] = (bf16_t)hn;
        if (xs_out) xs_out[off] = (bf16_t)hn;
    }
}

// ---------- generator GEMM: out[2048,32000](f32) = xs @ gen_W^T + gen_b ----------
__global__ __launch_bounds__(256) void k_gen(const bf16_t* __restrict__ xs,
                                             const bf16_t* __restrict__ gen_W,
                                             const float* __restrict__ gen_b,
                                             float* __restrict__ out) {
    __shared__ bf16_t sA[64 * 256];
    int tid = threadIdx.x, lane = tid & 63, w = tid >> 6;
    int m = lane & 15, q4 = lane >> 4;
    int m0 = blockIdx.x * 64, n0 = blockIdx.y * 256;
    f32x4 acc[4][4] = {};
    for (int ko = 0; ko < 2; ++ko) {
        __syncthreads();
#pragma unroll
        for (int it = 0; it < 8; ++it) {
            int idx = it * 256 + tid;
            int mr = idx >> 5, qc = idx & 31;
            bf16x8 v = *(const bf16x8*)(xs + (size_t)(m0 + mr) * 512 + ko * 256 + qc * 8);
            *(bf16x8*)(&sA[(mr * 32 + (qc ^ (mr & 7))) * 8]) = v;
        }
        __syncthreads();
        const bf16_t* bbase = gen_W + (size_t)(n0 + w * 64 + m) * 512 + ko * 256;
        for (int ks = 0; ks < 8; ++ks) {
            bf16x8 af[4];
#pragma unroll
            for (int mt = 0; mt < 4; ++mt) {
                int r = mt * 16 + m, chunk = ks * 4 + q4;
                af[mt] = *(const bf16x8*)(&sA[(r * 32 + (chunk ^ (r & 7))) * 8]);
            }
            int kc = ks * 32 + q4 * 8;
#pragma unroll
            for (int nt = 0; nt < 4; ++nt) {
                bf16x8 bfrag = *(const bf16x8*)(bbase + (size_t)nt * 16 * 512 + kc);
#pragma unroll
                for (int mt = 0; mt < 4; ++mt) acc[mt][nt] = MFMA(af[mt], bfrag, acc[mt][nt]);
            }
        }
    }
#pragma unroll
    for (int nt = 0; nt < 4; ++nt) {
        int col = n0 + w * 64 + nt * 16 + m;
        float bias = gen_b[col];
#pragma unroll
        for (int mt = 0; mt < 4; ++mt)
#pragma unroll
            for (int i = 0; i < 4; ++i) {
                int r = m0 + mt * 16 + q4 * 4 + i;
                out[(size_t)r * 32000 + col] = acc[mt][nt][i] + bias;
            }
    }
}

// ---------- tail: h_fin, c_fin (f32) ----------
__global__ void k_tail(const bf16_t* __restrict__ h_bf0, const float* __restrict__ c_f32,
                       float* __restrict__ out) {
    int idx = blockIdx.x * 256 + threadIdx.x;
    if (idx < 65536) {
        out[65536000 + idx] = (float)h_bf0[idx];
        out[65601536 + idx] = c_f32[idx];
    }
}

extern "C" void kernel_launch(void* const* d_in, const int* in_sizes, int n_in,
                              void* d_out, int out_size, void* d_ws, size_t ws_size,
                              hipStream_t stream) {
    const int* cur = (const int*)d_in[0];
    const float* h0 = (const float*)d_in[1];
    const float* c0 = (const float*)d_in[2];
    const float* enc = (const float*)d_in[3];
    const int* gt = (const int*)d_in[4];
    const float* emb = (const float*)d_in[6];
    const float* attn_W = (const float*)d_in[7];
    const float* attn_out_W = (const float*)d_in[8];
    const float* Wi = (const float*)d_in[9];
    const float* Wh = (const float*)d_in[10];
    const float* bi = (const float*)d_in[11];
    const float* bh = (const float*)d_in[12];
    const float* gen_W = (const float*)d_in[13];
    const float* gen_b = (const float*)d_in[14];
    float* out = (float*)d_out;

    char* ws = (char*)d_ws;
    float* c_f32 = (float*)(ws + 0);            // [2][64][512] f32
    bf16_t* h_bf = (bf16_t*)(ws + 262144);      // [2 parity][2 layer][64][512] bf16
    float* bsum = (float*)(ws + 524288);        // [2][2048] f32
    float* pre_s = (float*)(ws + 540672);       // [32][64][64] f32
    float* pre_r = (float*)(ws + 1064960);      // [32][64][512] f32
    bf16_t* rnn_bf = (bf16_t*)(ws + 5259264);   // [64][512] bf16
    bf16_t* xs = (bf16_t*)(ws + 5324800);       // [32][64][512] bf16
    bf16_t* attn_W_bf = (bf16_t*)(ws + 7421952);     // 65536
    bf16_t* attn_out_W_bf = (bf16_t*)(ws + 7553024); // 524288
    bf16_t* Wi_bf = (bf16_t*)(ws + 8601600);         // 2097152
    bf16_t* Wh_bf = (bf16_t*)(ws + 12795904);        // 2097152
    bf16_t* gen_W_bf = (bf16_t*)(ws + 16990208);     // 16384000

    k_cvt<<<32, 256, 0, stream>>>(attn_W, attn_W_bf, 65536);
    k_cvt<<<256, 256, 0, stream>>>(attn_out_W, attn_out_W_bf, 524288);
    k_cvt<<<1024, 256, 0, stream>>>(Wi, Wi_bf, 2097152);
    k_cvt<<<1024, 256, 0, stream>>>(Wh, Wh_bf, 2097152);
    k_cvt<<<8000, 256, 0, stream>>>(gen_W, gen_W_bf, 16384000);
    k_init<<<256, 256, 0, stream>>>(h0, c0, bi, bh, c_f32, h_bf, bsum);
    k_pre<<<dim3(32, 1), 256, 0, stream>>>(emb, cur, gt, attn_W_bf, 1024, 0, pre_s, 64);
    k_pre<<<dim3(32, 8), 256, 0, stream>>>(emb, cur, gt, attn_out_W_bf, 1024, 0, pre_r, 512);

    for (int t = 0; t < 32; ++t) {
        int p = t & 1;
        const bf16_t* hp = h_bf + (size_t)p * 65536;
        bf16_t* hn = h_bf + (size_t)(p ^ 1) * 65536;
        k_attn_rnn<<<8, 256, 0, stream>>>(t, hp + 32768, attn_W_bf, attn_out_W_bf, enc, pre_s, pre_r, rnn_bf);
        k_lstm<<<32, 256, 0, stream>>>(rnn_bf, hp, Wi_bf, Wh_bf, bsum, c_f32, hn, nullptr);
        k_lstm<<<32, 256, 0, stream>>>(hn, hp + 32768, Wi_bf + 1048576, Wh_bf + 1048576, bsum + 2048,
                                       c_f32 + 32768, hn + 32768, xs + (size_t)t * 32768);
    }
    k_gen<<<dim3(32, 125), 256, 0, stream>>>(xs, gen_W_bf, gen_b, out);
    k_tail<<<256, 256, 0, stream>>>(h_bf, c_f32, out);
}